// Round 3
// baseline (586.071 us; speedup 1.0000x reference)
//
#include <hip/hip_runtime.h>
#include <hip/hip_bf16.h>
#include <math.h>

// Problem constants (B,S,H,F,E,K) = (2,2048,1024,2048,8,2)
#define T_TOK 4096
#define HDIM  1024
#define FDIM  2048
#define EDIM  8
#define KSEL  2
#define TKROW 8192   // T*K
#define N2F   4096   // 2F
#define MAX_SLOTS 72 // = TK/128 + E = 72 ; also 72 = 8*9 exactly (clean XCD remap)

typedef __attribute__((ext_vector_type(8))) short short8;
typedef __attribute__((ext_vector_type(4))) float f32x4;

__device__ __forceinline__ unsigned short f32_to_bf16(float f) {
  unsigned int u = __float_as_uint(f);
  u += 0x7FFFu + ((u >> 16) & 1u);   // round-to-nearest-even
  return (unsigned short)(u >> 16);
}

// async global -> LDS, 16B per lane. LDS dest must be wave-uniform base + lane*16.
__device__ __forceinline__ void gload16(const void* g, void* l) {
  __builtin_amdgcn_global_load_lds(
      (const __attribute__((address_space(1))) unsigned int*)g,
      (__attribute__((address_space(3))) unsigned int*)l, 16, 0, 0);
}

// ---------------- conversion kernels ----------------

__global__ void conv_x_kernel(const float* __restrict__ x,
                              unsigned short* __restrict__ xb, int n) {
  int i = (blockIdx.x * blockDim.x + threadIdx.x) * 4;
  if (i < n) {
    float4 v = *(const float4*)(x + i);
    ushort4 o;
    o.x = f32_to_bf16(v.x); o.y = f32_to_bf16(v.y);
    o.z = f32_to_bf16(v.z); o.w = f32_to_bf16(v.w);
    *(ushort4*)(xb + i) = o;
  }
}

// in: [z][R][C] fp32 row-major; out: [z][C][R] bf16 row-major (transposed)
// write phase uses ushort2 (4B/lane) stores.
__global__ void transpose_conv_kernel(const float* __restrict__ in,
                                      unsigned short* __restrict__ out,
                                      int R, int C) {
  __shared__ float tile[64][65];
  long base = (long)blockIdx.z * (long)R * (long)C;
  int c0 = blockIdx.x * 64, r0 = blockIdx.y * 64;
  int tx = threadIdx.x & 63;   // contiguous dim
  int ty = threadIdx.x >> 6;   // 0..3
  #pragma unroll
  for (int j = 0; j < 64; j += 4) {
    int r = r0 + ty + j;
    tile[ty + j][tx] = in[base + (long)r * C + c0 + tx];
  }
  __syncthreads();
  int ow = threadIdx.x & 31;    // ushort2 index along R (covers 64 elems)
  int ocg = threadIdx.x >> 5;   // 0..7
  #pragma unroll
  for (int j = 0; j < 64; j += 8) {
    int oc = ocg + j;           // output row = c0+oc ; output col pair = r0+2*ow
    ushort2 o;
    o.x = f32_to_bf16(tile[2 * ow][oc]);
    o.y = f32_to_bf16(tile[2 * ow + 1][oc]);
    *(ushort2*)(out + base + (long)(c0 + oc) * R + r0 + 2 * ow) = o;
  }
}

// ---------------- router ----------------
__global__ void router_kernel(const float* __restrict__ x,
                              const float* __restrict__ wr,
                              int* __restrict__ eid, float* __restrict__ tgate,
                              float* __restrict__ p_sum,
                              float* __restrict__ lse2_sum,
                              int* __restrict__ counts) {
  __shared__ float s_p[EDIM];
  __shared__ float s_lse2;
  __shared__ int s_cnt[EDIM];
  if (threadIdx.x < EDIM) { s_p[threadIdx.x] = 0.f; s_cnt[threadIdx.x] = 0; }
  if (threadIdx.x == 0) s_lse2 = 0.f;
  __syncthreads();

  int wave = threadIdx.x >> 6;
  int lane = threadIdx.x & 63;

  for (int it = 0; it < 4; ++it) {
    int t = (blockIdx.x * 4 + wave) + it * 1024;
    float acc[EDIM];
    #pragma unroll
    for (int e = 0; e < EDIM; e++) acc[e] = 0.f;
    const float* xr = x + (long)t * HDIM;
    for (int h = lane; h < HDIM; h += 64) {
      float xv = xr[h];
      const float* w = wr + h * EDIM;
      #pragma unroll
      for (int e = 0; e < EDIM; e++) acc[e] += xv * w[e];
    }
    #pragma unroll
    for (int e = 0; e < EDIM; e++) {
      float v = acc[e];
      for (int off = 32; off > 0; off >>= 1) v += __shfl_down(v, off);
      acc[e] = v;
    }
    if (lane == 0) {
      float m = acc[0];
      #pragma unroll
      for (int e = 1; e < EDIM; e++) m = fmaxf(m, acc[e]);
      float ex[EDIM]; float se = 0.f;
      #pragma unroll
      for (int e = 0; e < EDIM; e++) { ex[e] = __expf(acc[e] - m); se += ex[e]; }
      float lse = m + __logf(se);
      atomicAdd(&s_lse2, lse * lse);
      float inv = 1.f / se;
      #pragma unroll
      for (int e = 0; e < EDIM; e++) atomicAdd(&s_p[e], ex[e] * inv);
      int i1 = 0;
      #pragma unroll
      for (int e = 1; e < EDIM; e++) if (acc[e] > acc[i1]) i1 = e;
      int i2 = (i1 == 0) ? 1 : 0;
      #pragma unroll
      for (int e = 0; e < EDIM; e++) if (e != i1 && acc[e] > acc[i2]) i2 = e;
      float g1 = 1.f / (1.f + __expf(acc[i2] - acc[i1]));
      eid[t * 2] = i1; eid[t * 2 + 1] = i2;
      tgate[t * 2] = g1; tgate[t * 2 + 1] = 1.f - g1;
      atomicAdd(&s_cnt[i1], 1); atomicAdd(&s_cnt[i2], 1);
    }
  }
  __syncthreads();
  if (threadIdx.x < EDIM) {
    atomicAdd(&p_sum[threadIdx.x], s_p[threadIdx.x]);
    atomicAdd(&counts[threadIdx.x], s_cnt[threadIdx.x]);
  }
  if (threadIdx.x == 0) atomicAdd(lse2_sum, s_lse2);
}

// ---------------- scan (1 thread) — 128-row slots ----------------
__global__ void scan_kernel(const int* __restrict__ counts,
                            int* __restrict__ offsets, int* __restrict__ slot_e,
                            int* __restrict__ slot_m0, int* __restrict__ slot_rows,
                            int* __restrict__ n_slots, int* __restrict__ cursors) {
  int off = 0, s = 0;
  for (int e = 0; e < EDIM; e++) {
    offsets[e] = off;
    cursors[e] = 0;
    int c = counts[e];
    for (int m0 = 0; m0 < c; m0 += 128) {
      slot_e[s] = e; slot_m0[s] = off + m0;
      slot_rows[s] = min(128, c - m0); s++;
    }
    off += c;
  }
  *n_slots = s;
}

// ---------------- scatter (block-aggregated, records positions) ----------------
__global__ void scatter_kernel(const int* __restrict__ eid,
                               const float* __restrict__ tgate,
                               const int* __restrict__ offsets,
                               int* __restrict__ cursors,
                               int* __restrict__ btok, float* __restrict__ bgate,
                               int* __restrict__ tpos) {
  __shared__ int lcnt[EDIM];
  __shared__ int lbase[EDIM];
  int tid = threadIdx.x;
  if (tid < EDIM) lcnt[tid] = 0;
  __syncthreads();
  int t = blockIdx.x * 256 + tid;
  int e0 = eid[t * 2], e1 = eid[t * 2 + 1];
  int p0 = atomicAdd(&lcnt[e0], 1);
  int p1 = atomicAdd(&lcnt[e1], 1);
  __syncthreads();
  if (tid < EDIM) lbase[tid] = atomicAdd(&cursors[tid], lcnt[tid]);
  __syncthreads();
  int r0 = offsets[e0] + lbase[e0] + p0;
  int r1 = offsets[e1] + lbase[e1] + p1;
  btok[r0] = t; bgate[r0] = tgate[t * 2];     tpos[t * 2] = r0;
  btok[r1] = t; bgate[r1] = tgate[t * 2 + 1]; tpos[t * 2 + 1] = r1;
}

// ---------------- GEMM1: glu = GLU(X_bucket @ w_in[e]) ----------------
// 128x128 tile, BK=64, 2-phase double-buffered global_load_lds pipeline:
// issue next tile's loads right after the barrier, compute current, one
// barrier per K-iter (drain overlaps with compute phase).
__global__ __launch_bounds__(256) void gemm1_kernel(
    const unsigned short* __restrict__ xb,      // [T][H] bf16
    const unsigned short* __restrict__ w_inT,   // [E][2F][H] bf16 (transposed)
    const int* __restrict__ btok,
    const int* __restrict__ slot_e, const int* __restrict__ slot_m0,
    const int* __restrict__ slot_rows, const int* __restrict__ n_slots,
    unsigned short* __restrict__ glu)           // [TK][F] bf16
{
  int bx = blockIdx.x;
  int slot = (bx & 7) * 9 + (bx >> 3);          // XCD-cluster: same-expert slots -> same XCD
  if (slot >= *n_slots) return;
  int e = slot_e[slot], r0 = slot_m0[slot], nrows = slot_rows[slot];
  int by = blockIdx.y;                          // 0..31 (64 glu cols per block)

  __shared__ unsigned short lA[2][128 * 64];    // 2 x 16 KiB
  __shared__ unsigned short lB[2][128 * 64];

  int tid = threadIdx.x;
  int lane = tid & 63, wv = tid >> 6;
  int wr = wv >> 1, wc = wv & 1;
  int lm = lane & 15, lq = lane >> 4, l7 = lane & 7;

  // staging: thread covers chunks ci = tid + i*256 ; row=ci>>3, kc_dest=ci&7
  // source is pre-swizzled: kc_src = kc_dest ^ (row&7)  (both-sides involution)
  int srow = tid >> 3, skc = tid & 7;
  const unsigned short* asrc[4];
  const unsigned short* bsrc[4];
  #pragma unroll
  for (int i = 0; i < 4; ++i) {
    int row = srow + i * 32;
    int swz = (skc ^ (row & 7)) * 8;            // bf16 elems
    int ar = min(row, nrows - 1);               // clamp: garbage rows masked at store
    int tok = btok[r0 + ar];
    asrc[i] = xb + (long)tok * HDIM + swz;
    // B row n -> w_inT row: per-32 interleave [a0-31][g0-31][a32-63][g32-63]
    int group = row >> 5, within = row & 31;
    int bcol = by * 64 + (group >> 1) * 32 + within + ((group & 1) ? FDIM : 0);
    bsrc[i] = w_inT + ((long)e * N2F + bcol) * HDIM + swz;
  }

  f32x4 acc[4][4];
  #pragma unroll
  for (int mf = 0; mf < 4; ++mf)
    #pragma unroll
    for (int nf = 0; nf < 4; ++nf) acc[mf][nf] = (f32x4){0.f, 0.f, 0.f, 0.f};

  // prologue: stage tile 0 into buf 0
  #pragma unroll
  for (int i = 0; i < 4; ++i) {
    gload16(asrc[i], &lA[0][tid * 8 + i * 2048]);
    gload16(bsrc[i], &lB[0][tid * 8 + i * 2048]);
  }
  int cur = 0;
  for (int it = 0; it < HDIM / 64; ++it) {
    __syncthreads();   // buf[cur] ready (drains in-flight loads)
    if (it + 1 < HDIM / 64) {
      int k0 = (it + 1) * 64;
      int nxt = cur ^ 1;
      #pragma unroll
      for (int i = 0; i < 4; ++i) {
        gload16(asrc[i] + k0, &lA[nxt][tid * 8 + i * 2048]);
        gload16(bsrc[i] + k0, &lB[nxt][tid * 8 + i * 2048]);
      }
    }
    #pragma unroll
    for (int ks = 0; ks < 2; ++ks) {
      short8 a[4], b[4];
      #pragma unroll
      for (int mf = 0; mf < 4; ++mf) {
        int row = wr * 64 + mf * 16 + lm;
        a[mf] = *(const short8*)&lA[cur][row * 64 + (((ks * 4 + lq) ^ l7) * 8)];
      }
      #pragma unroll
      for (int nf = 0; nf < 4; ++nf) {
        int n = wc * 64 + nf * 16 + lm;
        b[nf] = *(const short8*)&lB[cur][n * 64 + (((ks * 4 + lq) ^ l7) * 8)];
      }
      #pragma unroll
      for (int mf = 0; mf < 4; ++mf)
        #pragma unroll
        for (int nf = 0; nf < 4; ++nf)
          acc[mf][nf] = __builtin_amdgcn_mfma_f32_16x16x32_bf16(a[mf], b[nf], acc[mf][nf], 0, 0, 0);
    }
    cur ^= 1;
  }

  // epilogue: GLU pair: a = acc[mf][nf], g = acc[mf][nf+2]  (nf in {0,1})
  // output col = by*64 + wc*32 + nf*16 + lm
  #pragma unroll
  for (int mf = 0; mf < 4; ++mf) {
    #pragma unroll
    for (int r = 0; r < 4; ++r) {
      int row = wr * 64 + mf * 16 + lq * 4 + r;
      if (row < nrows) {
        #pragma unroll
        for (int nf = 0; nf < 2; ++nf) {
          float a = acc[mf][nf][r];
          float g = acc[mf][nf + 2][r];
          float val = (a / (1.f + __expf(-a))) * g;   // silu(a)*g
          glu[(long)(r0 + row) * FDIM + by * 64 + wc * 32 + nf * 16 + lm] = f32_to_bf16(val);
        }
      }
    }
  }
}

// ---------------- GEMM2: out_rows = gate * (glu @ w_out[e]) ----------------
// 128x128 tile, K=2048, 2-phase double-buffered pipeline, plain stores.
__global__ __launch_bounds__(256) void gemm2_kernel(
    const unsigned short* __restrict__ glu,     // [TK][F] bf16 (bucket order)
    const unsigned short* __restrict__ w_outT,  // [E][H][F] bf16 (transposed)
    const float* __restrict__ bgate,
    const int* __restrict__ slot_e, const int* __restrict__ slot_m0,
    const int* __restrict__ slot_rows, const int* __restrict__ n_slots,
    float* __restrict__ orows)                  // [TK][H] fp32
{
  int bx = blockIdx.x;
  int slot = (bx & 7) * 9 + (bx >> 3);
  if (slot >= *n_slots) return;
  int e = slot_e[slot], r0 = slot_m0[slot], nrows = slot_rows[slot];
  int c0 = blockIdx.y * 128;                    // 0..7 blocks

  __shared__ unsigned short lA[2][128 * 64];
  __shared__ unsigned short lB[2][128 * 64];

  int tid = threadIdx.x;
  int lane = tid & 63, wv = tid >> 6;
  int wr = wv >> 1, wc = wv & 1;
  int lm = lane & 15, lq = lane >> 4, l7 = lane & 7;

  int srow = tid >> 3, skc = tid & 7;
  const unsigned short* asrc[4];
  const unsigned short* bsrc[4];
  #pragma unroll
  for (int i = 0; i < 4; ++i) {
    int row = srow + i * 32;
    int swz = (skc ^ (row & 7)) * 8;
    int ar = min(row, nrows - 1);
    asrc[i] = glu + (long)(r0 + ar) * FDIM + swz;
    bsrc[i] = w_outT + ((long)e * HDIM + c0 + row) * FDIM + swz;
  }

  f32x4 acc[4][4];
  #pragma unroll
  for (int mf = 0; mf < 4; ++mf)
    #pragma unroll
    for (int nf = 0; nf < 4; ++nf) acc[mf][nf] = (f32x4){0.f, 0.f, 0.f, 0.f};

  #pragma unroll
  for (int i = 0; i < 4; ++i) {
    gload16(asrc[i], &lA[0][tid * 8 + i * 2048]);
    gload16(bsrc[i], &lB[0][tid * 8 + i * 2048]);
  }
  int cur = 0;
  for (int it = 0; it < FDIM / 64; ++it) {
    __syncthreads();
    if (it + 1 < FDIM / 64) {
      int k0 = (it + 1) * 64;
      int nxt = cur ^ 1;
      #pragma unroll
      for (int i = 0; i < 4; ++i) {
        gload16(asrc[i] + k0, &lA[nxt][tid * 8 + i * 2048]);
        gload16(bsrc[i] + k0, &lB[nxt][tid * 8 + i * 2048]);
      }
    }
    #pragma unroll
    for (int ks = 0; ks < 2; ++ks) {
      short8 a[4], b[4];
      #pragma unroll
      for (int mf = 0; mf < 4; ++mf) {
        int row = wr * 64 + mf * 16 + lm;
        a[mf] = *(const short8*)&lA[cur][row * 64 + (((ks * 4 + lq) ^ l7) * 8)];
      }
      #pragma unroll
      for (int nf = 0; nf < 4; ++nf) {
        int n = wc * 64 + nf * 16 + lm;
        b[nf] = *(const short8*)&lB[cur][n * 64 + (((ks * 4 + lq) ^ l7) * 8)];
      }
      #pragma unroll
      for (int mf = 0; mf < 4; ++mf)
        #pragma unroll
        for (int nf = 0; nf < 4; ++nf)
          acc[mf][nf] = __builtin_amdgcn_mfma_f32_16x16x32_bf16(a[mf], b[nf], acc[mf][nf], 0, 0, 0);
    }
    cur ^= 1;
  }

  #pragma unroll
  for (int mf = 0; mf < 4; ++mf) {
    #pragma unroll
    for (int r = 0; r < 4; ++r) {
      int row = wr * 64 + mf * 16 + lq * 4 + r;
      if (row < nrows) {
        float g = bgate[r0 + row];
        #pragma unroll
        for (int nf = 0; nf < 4; ++nf) {
          orows[(long)(r0 + row) * HDIM + c0 + wc * 64 + nf * 16 + lm] = acc[mf][nf][r] * g;
        }
      }
    }
  }
}

// ---------------- combine: y[t] = bias + orows[pos0] + orows[pos1] ----------------
__global__ void combine_kernel(const float* __restrict__ orows,
                               const int* __restrict__ tpos,
                               const float* __restrict__ bias,
                               float* __restrict__ y) {
  int i = blockIdx.x * 256 + threadIdx.x;   // over T*H/4
  int t = i >> 8;                            // HDIM/4 = 256 float4 per token
  int h = (i & 255) * 4;
  int p0 = tpos[t * 2], p1 = tpos[t * 2 + 1];
  float4 a = *(const float4*)(orows + (long)p0 * HDIM + h);
  float4 b = *(const float4*)(orows + (long)p1 * HDIM + h);
  float4 bv = *(const float4*)(bias + h);
  float4 o;
  o.x = a.x + b.x + bv.x; o.y = a.y + b.y + bv.y;
  o.z = a.z + b.z + bv.z; o.w = a.w + b.w + bv.w;
  *(float4*)(y + (long)t * HDIM + h) = o;
}

// ---------------- finalize loss ----------------
__global__ void finalize_kernel(const float* __restrict__ p_sum,
                                const float* __restrict__ lse2,
                                const int* __restrict__ counts,
                                float* __restrict__ loss_out) {
  float P = 0.f;
  for (int e = 0; e < EDIM; e++) P += p_sum[e];
  float dot = 0.f;
  for (int e = 0; e < EDIM; e++)
    dot += (p_sum[e] / P) * ((float)counts[e] / (float)TKROW);
  *loss_out = (float)EDIM * dot + 0.1f * (*lse2) / (float)T_TOK;
}

// ---------------- host launch ----------------
extern "C" void kernel_launch(void* const* d_in, const int* in_sizes, int n_in,
                              void* d_out, int out_size, void* d_ws, size_t ws_size,
                              hipStream_t stream) {
  const float* x        = (const float*)d_in[0];
  const float* w_router = (const float*)d_in[1];
  const float* w_in     = (const float*)d_in[2];
  const float* w_out    = (const float*)d_in[3];
  const float* bias     = (const float*)d_in[4];
  float* y = (float*)d_out;                  // [T*H] then loss at [T*H]

  char* ws = (char*)d_ws;
  size_t o = 0;
  auto alloc = [&](size_t bytes) { size_t r = o; o = (o + bytes + 255) & ~(size_t)255; return r; };
  size_t o_meta    = alloc(256);              // p_sum[8],lse2,counts[8],cursors[8],n_slots
  size_t o_offsets = alloc(EDIM * 4);
  size_t o_slot_e  = alloc(MAX_SLOTS * 4);
  size_t o_slot_m0 = alloc(MAX_SLOTS * 4);
  size_t o_slot_nr = alloc(MAX_SLOTS * 4);
  size_t o_eid     = alloc((size_t)T_TOK * 2 * 4);
  size_t o_tgate   = alloc((size_t)T_TOK * 2 * 4);
  size_t o_tpos    = alloc((size_t)T_TOK * 2 * 4);
  size_t o_btok    = alloc((size_t)TKROW * 4);
  size_t o_bgate   = alloc((size_t)TKROW * 4);
  size_t o_xb      = alloc((size_t)T_TOK * HDIM * 2);
  size_t o_winT    = alloc((size_t)EDIM * N2F * HDIM * 2);  // 64 MiB
  size_t o_woutT   = alloc((size_t)EDIM * HDIM * FDIM * 2); // 32 MiB
  size_t o_glu     = alloc((size_t)TKROW * FDIM * 2);       // 32 MiB
  // orows (32 MiB) ALIASES winT: winT is dead after gemm1, orows is written by
  // gemm2 and read by combine, both strictly later in stream order. Keeps the
  // total workspace footprint at the proven-safe ~136.5 MiB (round-0 size).
  size_t o_orows   = o_winT;
  (void)ws_size;

  float* p_sum   = (float*)(ws + o_meta);
  float* lse2    = (float*)(ws + o_meta + 32);
  int*   counts  = (int*)(ws + o_meta + 64);
  int*   cursors = (int*)(ws + o_meta + 96);
  int*   n_slots = (int*)(ws + o_meta + 128);
  int*   offsets = (int*)(ws + o_offsets);
  int*   slot_e  = (int*)(ws + o_slot_e);
  int*   slot_m0 = (int*)(ws + o_slot_m0);
  int*   slot_nr = (int*)(ws + o_slot_nr);
  int*   eid     = (int*)(ws + o_eid);
  float* tgate   = (float*)(ws + o_tgate);
  int*   tpos    = (int*)(ws + o_tpos);
  int*   btok    = (int*)(ws + o_btok);
  float* bgate   = (float*)(ws + o_bgate);
  unsigned short* xb    = (unsigned short*)(ws + o_xb);
  unsigned short* winT  = (unsigned short*)(ws + o_winT);
  unsigned short* woutT = (unsigned short*)(ws + o_woutT);
  unsigned short* glu   = (unsigned short*)(ws + o_glu);
  float* orows = (float*)(ws + o_orows);

  hipMemsetAsync(ws, 0, 256, stream);

  // conversions
  conv_x_kernel<<<dim3((T_TOK * HDIM) / 1024), dim3(256), 0, stream>>>(
      x, xb, T_TOK * HDIM);
  transpose_conv_kernel<<<dim3(N2F / 64, HDIM / 64, EDIM), dim3(256), 0, stream>>>(
      w_in, winT, HDIM, N2F);
  transpose_conv_kernel<<<dim3(HDIM / 64, FDIM / 64, EDIM), dim3(256), 0, stream>>>(
      w_out, woutT, FDIM, HDIM);

  // routing
  router_kernel<<<dim3(256), dim3(256), 0, stream>>>(
      x, w_router, eid, tgate, p_sum, lse2, counts);
  scan_kernel<<<dim3(1), dim3(1), 0, stream>>>(
      counts, offsets, slot_e, slot_m0, slot_nr, n_slots, cursors);
  scatter_kernel<<<dim3(T_TOK / 256), dim3(256), 0, stream>>>(
      eid, tgate, offsets, cursors, btok, bgate, tpos);

  // expert GEMMs (gemm1 reads winT; gemm2 then overwrites that region as orows)
  gemm1_kernel<<<dim3(MAX_SLOTS, FDIM / 64), dim3(256), 0, stream>>>(
      xb, winT, btok, slot_e, slot_m0, slot_nr, n_slots, glu);
  gemm2_kernel<<<dim3(MAX_SLOTS, HDIM / 128), dim3(256), 0, stream>>>(
      glu, woutT, bgate, slot_e, slot_m0, slot_nr, n_slots, orows);

  // combine + loss
  combine_kernel<<<dim3((T_TOK * HDIM) / 1024), dim3(256), 0, stream>>>(
      orows, tpos, bias, y);
  finalize_kernel<<<dim3(1), dim3(1), 0, stream>>>(
      p_sum, lse2, counts, y + (size_t)T_TOK * HDIM);
}

// Round 5
// 559.789 us; speedup vs baseline: 1.0469x; 1.0469x over previous
//
#include <hip/hip_runtime.h>
#include <hip/hip_bf16.h>
#include <math.h>

// Problem constants (B,S,H,F,E,K) = (2,2048,1024,2048,8,2)
#define T_TOK 4096
#define HDIM  1024
#define FDIM  2048
#define EDIM  8
#define KSEL  2
#define TKROW 8192   // T*K
#define N2F   4096   // 2F
#define MAX_SLOTS 72 // = TK/128 + E = 72 ; also 72 = 8*9 exactly (clean XCD remap)

typedef __attribute__((ext_vector_type(8))) short short8;
typedef __attribute__((ext_vector_type(4))) float f32x4;

__device__ __forceinline__ unsigned short f32_to_bf16(float f) {
  unsigned int u = __float_as_uint(f);
  u += 0x7FFFu + ((u >> 16) & 1u);   // round-to-nearest-even
  return (unsigned short)(u >> 16);
}

// async global -> LDS, 16B per lane. LDS dest must be wave-uniform base + lane*16.
__device__ __forceinline__ void gload16(const void* g, void* l) {
  __builtin_amdgcn_global_load_lds(
      (const __attribute__((address_space(1))) unsigned int*)g,
      (__attribute__((address_space(3))) unsigned int*)l, 16, 0, 0);
}

// ---------------- conversion kernels ----------------

// in: [z][R][C] fp32 row-major; out: [z][C][R] bf16 row-major (transposed)
// write phase uses ushort2 (4B/lane) stores.
__global__ void transpose_conv_kernel(const float* __restrict__ in,
                                      unsigned short* __restrict__ out,
                                      int R, int C) {
  __shared__ float tile[64][65];
  long base = (long)blockIdx.z * (long)R * (long)C;
  int c0 = blockIdx.x * 64, r0 = blockIdx.y * 64;
  int tx = threadIdx.x & 63;   // contiguous dim
  int ty = threadIdx.x >> 6;   // 0..3
  #pragma unroll
  for (int j = 0; j < 64; j += 4) {
    int r = r0 + ty + j;
    tile[ty + j][tx] = in[base + (long)r * C + c0 + tx];
  }
  __syncthreads();
  int ow = threadIdx.x & 31;    // ushort2 index along R (covers 64 elems)
  int ocg = threadIdx.x >> 5;   // 0..7
  #pragma unroll
  for (int j = 0; j < 64; j += 8) {
    int oc = ocg + j;           // output row = c0+oc ; output col pair = r0+2*ow
    ushort2 o;
    o.x = f32_to_bf16(tile[2 * ow][oc]);
    o.y = f32_to_bf16(tile[2 * ow + 1][oc]);
    *(ushort2*)(out + base + (long)(c0 + oc) * R + r0 + 2 * ow) = o;
  }
}

// ---------------- router (fused: also emits xb bf16 copy of x) ----------------
__global__ void router_kernel(const float* __restrict__ x,
                              const float* __restrict__ wr,
                              unsigned short* __restrict__ xbout,
                              int* __restrict__ eid, float* __restrict__ tgate,
                              float* __restrict__ p_sum,
                              float* __restrict__ lse2_sum,
                              int* __restrict__ counts) {
  __shared__ float s_p[EDIM];
  __shared__ float s_lse2;
  __shared__ int s_cnt[EDIM];
  if (threadIdx.x < EDIM) { s_p[threadIdx.x] = 0.f; s_cnt[threadIdx.x] = 0; }
  if (threadIdx.x == 0) s_lse2 = 0.f;
  __syncthreads();

  int wave = threadIdx.x >> 6;
  int lane = threadIdx.x & 63;

  for (int it = 0; it < 4; ++it) {
    int t = (blockIdx.x * 4 + wave) + it * 1024;
    float acc[EDIM];
    #pragma unroll
    for (int e = 0; e < EDIM; e++) acc[e] = 0.f;
    const float* xr = x + (long)t * HDIM;
    unsigned short* xo = xbout + (long)t * HDIM;
    #pragma unroll
    for (int c = 0; c < 4; ++c) {
      int h0 = lane * 4 + c * 256;
      float4 v = *(const float4*)(xr + h0);
      ushort4 o;
      o.x = f32_to_bf16(v.x); o.y = f32_to_bf16(v.y);
      o.z = f32_to_bf16(v.z); o.w = f32_to_bf16(v.w);
      *(ushort4*)(xo + h0) = o;
      const float* w0 = wr + (long)h0 * EDIM;
      #pragma unroll
      for (int e = 0; e < EDIM; e++)
        acc[e] += v.x * w0[e] + v.y * w0[EDIM + e] +
                  v.z * w0[2 * EDIM + e] + v.w * w0[3 * EDIM + e];
    }
    #pragma unroll
    for (int e = 0; e < EDIM; e++) {
      float v = acc[e];
      for (int off = 32; off > 0; off >>= 1) v += __shfl_down(v, off);
      acc[e] = v;
    }
    if (lane == 0) {
      float m = acc[0];
      #pragma unroll
      for (int e = 1; e < EDIM; e++) m = fmaxf(m, acc[e]);
      float ex[EDIM]; float se = 0.f;
      #pragma unroll
      for (int e = 0; e < EDIM; e++) { ex[e] = __expf(acc[e] - m); se += ex[e]; }
      float lse = m + __logf(se);
      atomicAdd(&s_lse2, lse * lse);
      float inv = 1.f / se;
      #pragma unroll
      for (int e = 0; e < EDIM; e++) atomicAdd(&s_p[e], ex[e] * inv);
      int i1 = 0;
      #pragma unroll
      for (int e = 1; e < EDIM; e++) if (acc[e] > acc[i1]) i1 = e;
      int i2 = (i1 == 0) ? 1 : 0;
      #pragma unroll
      for (int e = 0; e < EDIM; e++) if (e != i1 && acc[e] > acc[i2]) i2 = e;
      float g1 = 1.f / (1.f + __expf(acc[i2] - acc[i1]));
      eid[t * 2] = i1; eid[t * 2 + 1] = i2;
      tgate[t * 2] = g1; tgate[t * 2 + 1] = 1.f - g1;
      atomicAdd(&s_cnt[i1], 1); atomicAdd(&s_cnt[i2], 1);
    }
  }
  __syncthreads();
  if (threadIdx.x < EDIM) {
    atomicAdd(&p_sum[threadIdx.x], s_p[threadIdx.x]);
    atomicAdd(&counts[threadIdx.x], s_cnt[threadIdx.x]);
  }
  if (threadIdx.x == 0) atomicAdd(lse2_sum, s_lse2);
}

// ---------------- scan (1 thread) — 128-row slots ----------------
__global__ void scan_kernel(const int* __restrict__ counts,
                            int* __restrict__ offsets, int* __restrict__ slot_e,
                            int* __restrict__ slot_m0, int* __restrict__ slot_rows,
                            int* __restrict__ n_slots, int* __restrict__ cursors) {
  int off = 0, s = 0;
  for (int e = 0; e < EDIM; e++) {
    offsets[e] = off;
    cursors[e] = 0;
    int c = counts[e];
    for (int m0 = 0; m0 < c; m0 += 128) {
      slot_e[s] = e; slot_m0[s] = off + m0;
      slot_rows[s] = min(128, c - m0); s++;
    }
    off += c;
  }
  *n_slots = s;
}

// ---------------- scatter (block-aggregated, records positions) ----------------
__global__ void scatter_kernel(const int* __restrict__ eid,
                               const float* __restrict__ tgate,
                               const int* __restrict__ offsets,
                               int* __restrict__ cursors,
                               int* __restrict__ btok, float* __restrict__ bgate,
                               int* __restrict__ tpos) {
  __shared__ int lcnt[EDIM];
  __shared__ int lbase[EDIM];
  int tid = threadIdx.x;
  if (tid < EDIM) lcnt[tid] = 0;
  __syncthreads();
  int t = blockIdx.x * 256 + tid;
  int e0 = eid[t * 2], e1 = eid[t * 2 + 1];
  int p0 = atomicAdd(&lcnt[e0], 1);
  int p1 = atomicAdd(&lcnt[e1], 1);
  __syncthreads();
  if (tid < EDIM) lbase[tid] = atomicAdd(&cursors[tid], lcnt[tid]);
  __syncthreads();
  int r0 = offsets[e0] + lbase[e0] + p0;
  int r1 = offsets[e1] + lbase[e1] + p1;
  btok[r0] = t; bgate[r0] = tgate[t * 2];     tpos[t * 2] = r0;
  btok[r1] = t; bgate[r1] = tgate[t * 2 + 1]; tpos[t * 2 + 1] = r1;
}

// ---------------- GEMM1: glu = GLU(X_bucket @ w_in[e]) ----------------
// 128 rows x 128 glu-cols per block (256 w_inT rows staged), BK=64.
// Verified round-2 sync template (single buffer + __syncthreads), doubled
// compute per barrier-drain. 4 waves in 2x2; both-sides XOR swizzle.
__global__ __launch_bounds__(256) void gemm1_kernel(
    const unsigned short* __restrict__ xb,      // [T][H] bf16
    const unsigned short* __restrict__ w_inT,   // [E][2F][H] bf16 (transposed)
    const int* __restrict__ btok,
    const int* __restrict__ slot_e, const int* __restrict__ slot_m0,
    const int* __restrict__ slot_rows, const int* __restrict__ n_slots,
    unsigned short* __restrict__ glu)           // [TK][F] bf16
{
  int bx = blockIdx.x;
  int slot = (bx & 7) * 9 + (bx >> 3);          // XCD-cluster: same-expert slots -> same XCD
  if (slot >= *n_slots) return;
  int e = slot_e[slot], r0 = slot_m0[slot], nrows = slot_rows[slot];
  int by = blockIdx.y;                          // 0..15 (128 glu cols per block)

  __shared__ unsigned short lA[128 * 64];       // 16 KiB, linear (gload dest)
  __shared__ unsigned short lB[256 * 64];       // 32 KiB

  int tid = threadIdx.x;
  int lane = tid & 63, wv = tid >> 6;
  int wr = wv >> 1, wc = wv & 1;
  int lm = lane & 15, lq = lane >> 4, l7 = lane & 7;

  // staging: thread covers chunks ci = tid + i*256 ; row=ci>>3, kc_dest=ci&7
  // source is pre-swizzled: kc_src = kc_dest ^ (row&7)  (both-sides involution)
  int srow = tid >> 3, skc = tid & 7;
  const unsigned short* asrc[4];
  const unsigned short* bsrc[8];
  #pragma unroll
  for (int i = 0; i < 4; ++i) {
    int row = srow + i * 32;
    int swz = (skc ^ (row & 7)) * 8;            // bf16 elems
    int ar = min(row, nrows - 1);               // clamp: garbage rows masked at store
    int tok = btok[r0 + ar];
    asrc[i] = xb + (long)tok * HDIM + swz;
  }
  // lB row n (0..255): w = n>>7 (wave-col), r = n&127.
  // r<64 -> a-col = by*128 + w*64 + r ; r>=64 -> g-col = FDIM + by*128 + w*64 + (r-64)
  #pragma unroll
  for (int i = 0; i < 8; ++i) {
    int row = srow + i * 32;
    int swz = (skc ^ (row & 7)) * 8;
    int w = row >> 7, r = row & 127;
    int bcol = (r < 64) ? (by * 128 + w * 64 + r)
                        : (FDIM + by * 128 + w * 64 + (r - 64));
    bsrc[i] = w_inT + ((long)e * N2F + bcol) * HDIM + swz;
  }

  f32x4 acc[4][8];
  #pragma unroll
  for (int mf = 0; mf < 4; ++mf)
    #pragma unroll
    for (int nf = 0; nf < 8; ++nf) acc[mf][nf] = (f32x4){0.f, 0.f, 0.f, 0.f};

  for (int k0 = 0; k0 < HDIM; k0 += 64) {
    #pragma unroll
    for (int i = 0; i < 4; ++i) gload16(asrc[i] + k0, &lA[tid * 8 + i * 2048]);
    #pragma unroll
    for (int i = 0; i < 8; ++i) gload16(bsrc[i] + k0, &lB[tid * 8 + i * 2048]);
    __syncthreads();   // compiler drains vmcnt before s_barrier
    #pragma unroll
    for (int ks = 0; ks < 2; ++ks) {
      short8 a[4];
      #pragma unroll
      for (int mf = 0; mf < 4; ++mf) {
        int row = wr * 64 + mf * 16 + lm;
        a[mf] = *(const short8*)&lA[row * 64 + (((ks * 4 + lq) ^ l7) * 8)];
      }
      #pragma unroll
      for (int nf = 0; nf < 8; ++nf) {
        int n = wc * 128 + nf * 16 + lm;
        short8 b = *(const short8*)&lB[n * 64 + (((ks * 4 + lq) ^ l7) * 8)];
        #pragma unroll
        for (int mf = 0; mf < 4; ++mf)
          acc[mf][nf] = __builtin_amdgcn_mfma_f32_16x16x32_bf16(a[mf], b, acc[mf][nf], 0, 0, 0);
      }
    }
    __syncthreads();
  }

  // epilogue: GLU pair: a = acc[mf][nf], g = acc[mf][nf+4]  (nf in 0..3)
  // output col = by*128 + wc*64 + nf*16 + lm
  #pragma unroll
  for (int mf = 0; mf < 4; ++mf) {
    #pragma unroll
    for (int r = 0; r < 4; ++r) {
      int row = wr * 64 + mf * 16 + lq * 4 + r;
      if (row < nrows) {
        #pragma unroll
        for (int nf = 0; nf < 4; ++nf) {
          float a = acc[mf][nf][r];
          float g = acc[mf][nf + 4][r];
          float val = (a / (1.f + __expf(-a))) * g;   // silu(a)*g
          glu[(long)(r0 + row) * FDIM + by * 128 + wc * 64 + nf * 16 + lm] = f32_to_bf16(val);
        }
      }
    }
  }
}

// ---------------- GEMM2: out_rows = gate * (glu @ w_out[e]) ----------------
// 128x128 tile, K=2048, verified round-2 template, plain stores (no atomics).
__global__ __launch_bounds__(256) void gemm2_kernel(
    const unsigned short* __restrict__ glu,     // [TK][F] bf16 (bucket order)
    const unsigned short* __restrict__ w_outT,  // [E][H][F] bf16 (transposed)
    const float* __restrict__ bgate,
    const int* __restrict__ slot_e, const int* __restrict__ slot_m0,
    const int* __restrict__ slot_rows, const int* __restrict__ n_slots,
    float* __restrict__ orows)                  // [TK][H] fp32
{
  int bx = blockIdx.x;
  int slot = (bx & 7) * 9 + (bx >> 3);
  if (slot >= *n_slots) return;
  int e = slot_e[slot], r0 = slot_m0[slot], nrows = slot_rows[slot];
  int c0 = blockIdx.y * 128;                    // 0..7 blocks

  __shared__ unsigned short lA[128 * 64];
  __shared__ unsigned short lB[128 * 64];

  int tid = threadIdx.x;
  int lane = tid & 63, wv = tid >> 6;
  int wr = wv >> 1, wc = wv & 1;
  int lm = lane & 15, lq = lane >> 4, l7 = lane & 7;

  int srow = tid >> 3, skc = tid & 7;
  const unsigned short* asrc[4];
  const unsigned short* bsrc[4];
  #pragma unroll
  for (int i = 0; i < 4; ++i) {
    int row = srow + i * 32;
    int swz = (skc ^ (row & 7)) * 8;
    int ar = min(row, nrows - 1);
    asrc[i] = glu + (long)(r0 + ar) * FDIM + swz;
    bsrc[i] = w_outT + ((long)e * HDIM + c0 + row) * FDIM + swz;
  }

  f32x4 acc[4][4];
  #pragma unroll
  for (int mf = 0; mf < 4; ++mf)
    #pragma unroll
    for (int nf = 0; nf < 4; ++nf) acc[mf][nf] = (f32x4){0.f, 0.f, 0.f, 0.f};

  for (int k0 = 0; k0 < FDIM; k0 += 64) {
    #pragma unroll
    for (int i = 0; i < 4; ++i) {
      gload16(asrc[i] + k0, &lA[tid * 8 + i * 2048]);
      gload16(bsrc[i] + k0, &lB[tid * 8 + i * 2048]);
    }
    __syncthreads();
    #pragma unroll
    for (int ks = 0; ks < 2; ++ks) {
      short8 a[4], b[4];
      #pragma unroll
      for (int mf = 0; mf < 4; ++mf) {
        int row = wr * 64 + mf * 16 + lm;
        a[mf] = *(const short8*)&lA[row * 64 + (((ks * 4 + lq) ^ l7) * 8)];
      }
      #pragma unroll
      for (int nf = 0; nf < 4; ++nf) {
        int n = wc * 64 + nf * 16 + lm;
        b[nf] = *(const short8*)&lB[n * 64 + (((ks * 4 + lq) ^ l7) * 8)];
      }
      #pragma unroll
      for (int mf = 0; mf < 4; ++mf)
        #pragma unroll
        for (int nf = 0; nf < 4; ++nf)
          acc[mf][nf] = __builtin_amdgcn_mfma_f32_16x16x32_bf16(a[mf], b[nf], acc[mf][nf], 0, 0, 0);
    }
    __syncthreads();
  }

  #pragma unroll
  for (int mf = 0; mf < 4; ++mf) {
    #pragma unroll
    for (int r = 0; r < 4; ++r) {
      int row = wr * 64 + mf * 16 + lq * 4 + r;
      if (row < nrows) {
        float g = bgate[r0 + row];
        #pragma unroll
        for (int nf = 0; nf < 4; ++nf) {
          orows[(long)(r0 + row) * HDIM + c0 + wc * 64 + nf * 16 + lm] = acc[mf][nf][r] * g;
        }
      }
    }
  }
}

// ---------------- combine: y[t] = bias + orows[pos0] + orows[pos1] ----------------
__global__ void combine_kernel(const float* __restrict__ orows,
                               const int* __restrict__ tpos,
                               const float* __restrict__ bias,
                               float* __restrict__ y) {
  int i = blockIdx.x * 256 + threadIdx.x;   // over T*H/4
  int t = i >> 8;                            // HDIM/4 = 256 float4 per token
  int h = (i & 255) * 4;
  int p0 = tpos[t * 2], p1 = tpos[t * 2 + 1];
  float4 a = *(const float4*)(orows + (long)p0 * HDIM + h);
  float4 b = *(const float4*)(orows + (long)p1 * HDIM + h);
  float4 bv = *(const float4*)(bias + h);
  float4 o;
  o.x = a.x + b.x + bv.x; o.y = a.y + b.y + bv.y;
  o.z = a.z + b.z + bv.z; o.w = a.w + b.w + bv.w;
  *(float4*)(y + (long)t * HDIM + h) = o;
}

// ---------------- finalize loss ----------------
__global__ void finalize_kernel(const float* __restrict__ p_sum,
                                const float* __restrict__ lse2,
                                const int* __restrict__ counts,
                                float* __restrict__ loss_out) {
  float P = 0.f;
  for (int e = 0; e < EDIM; e++) P += p_sum[e];
  float dot = 0.f;
  for (int e = 0; e < EDIM; e++)
    dot += (p_sum[e] / P) * ((float)counts[e] / (float)TKROW);
  *loss_out = (float)EDIM * dot + 0.1f * (*lse2) / (float)T_TOK;
}

// ---------------- host launch ----------------
extern "C" void kernel_launch(void* const* d_in, const int* in_sizes, int n_in,
                              void* d_out, int out_size, void* d_ws, size_t ws_size,
                              hipStream_t stream) {
  const float* x        = (const float*)d_in[0];
  const float* w_router = (const float*)d_in[1];
  const float* w_in     = (const float*)d_in[2];
  const float* w_out    = (const float*)d_in[3];
  const float* bias     = (const float*)d_in[4];
  float* y = (float*)d_out;                  // [T*H] then loss at [T*H]

  char* ws = (char*)d_ws;
  size_t o = 0;
  auto alloc = [&](size_t bytes) { size_t r = o; o = (o + bytes + 255) & ~(size_t)255; return r; };
  size_t o_meta    = alloc(256);              // p_sum[8],lse2,counts[8],cursors[8],n_slots
  size_t o_offsets = alloc(EDIM * 4);
  size_t o_slot_e  = alloc(MAX_SLOTS * 4);
  size_t o_slot_m0 = alloc(MAX_SLOTS * 4);
  size_t o_slot_nr = alloc(MAX_SLOTS * 4);
  size_t o_eid     = alloc((size_t)T_TOK * 2 * 4);
  size_t o_tgate   = alloc((size_t)T_TOK * 2 * 4);
  size_t o_tpos    = alloc((size_t)T_TOK * 2 * 4);
  size_t o_btok    = alloc((size_t)TKROW * 4);
  size_t o_bgate   = alloc((size_t)TKROW * 4);
  size_t o_xb      = alloc((size_t)T_TOK * HDIM * 2);
  size_t o_winT    = alloc((size_t)EDIM * N2F * HDIM * 2);  // 64 MiB
  size_t o_woutT   = alloc((size_t)EDIM * HDIM * FDIM * 2); // 32 MiB
  size_t o_glu     = alloc((size_t)TKROW * FDIM * 2);       // 32 MiB
  // orows (32 MiB) ALIASES winT: winT is dead after gemm1, orows is written by
  // gemm2 and read by combine, both strictly later in stream order. Keeps the
  // total workspace footprint at the proven-safe ~136.5 MiB (round-0 size).
  size_t o_orows   = o_winT;
  (void)ws_size;

  float* p_sum   = (float*)(ws + o_meta);
  float* lse2    = (float*)(ws + o_meta + 32);
  int*   counts  = (int*)(ws + o_meta + 64);
  int*   cursors = (int*)(ws + o_meta + 96);
  int*   n_slots = (int*)(ws + o_meta + 128);
  int*   offsets = (int*)(ws + o_offsets);
  int*   slot_e  = (int*)(ws + o_slot_e);
  int*   slot_m0 = (int*)(ws + o_slot_m0);
  int*   slot_nr = (int*)(ws + o_slot_nr);
  int*   eid     = (int*)(ws + o_eid);
  float* tgate   = (float*)(ws + o_tgate);
  int*   tpos    = (int*)(ws + o_tpos);
  int*   btok    = (int*)(ws + o_btok);
  float* bgate   = (float*)(ws + o_bgate);
  unsigned short* xb    = (unsigned short*)(ws + o_xb);
  unsigned short* winT  = (unsigned short*)(ws + o_winT);
  unsigned short* woutT = (unsigned short*)(ws + o_woutT);
  unsigned short* glu   = (unsigned short*)(ws + o_glu);
  float* orows = (float*)(ws + o_orows);

  hipMemsetAsync(ws, 0, 256, stream);

  // weight conversions
  transpose_conv_kernel<<<dim3(N2F / 64, HDIM / 64, EDIM), dim3(256), 0, stream>>>(
      w_in, winT, HDIM, N2F);
  transpose_conv_kernel<<<dim3(HDIM / 64, FDIM / 64, EDIM), dim3(256), 0, stream>>>(
      w_out, woutT, FDIM, HDIM);

  // routing (also produces xb, the bf16 copy of x)
  router_kernel<<<dim3(256), dim3(256), 0, stream>>>(
      x, w_router, xb, eid, tgate, p_sum, lse2, counts);
  scan_kernel<<<dim3(1), dim3(1), 0, stream>>>(
      counts, offsets, slot_e, slot_m0, slot_nr, n_slots, cursors);
  scatter_kernel<<<dim3(T_TOK / 256), dim3(256), 0, stream>>>(
      eid, tgate, offsets, cursors, btok, bgate, tpos);

  // expert GEMMs (gemm1 reads winT; gemm2 then overwrites that region as orows)
  gemm1_kernel<<<dim3(MAX_SLOTS, FDIM / 128), dim3(256), 0, stream>>>(
      xb, winT, btok, slot_e, slot_m0, slot_nr, n_slots, glu);
  gemm2_kernel<<<dim3(MAX_SLOTS, HDIM / 128), dim3(256), 0, stream>>>(
      glu, woutT, bgate, slot_e, slot_m0, slot_nr, n_slots, orows);

  // combine + loss
  combine_kernel<<<dim3((T_TOK * HDIM) / 1024), dim3(256), 0, stream>>>(
      orows, tpos, bias, y);
  finalize_kernel<<<dim3(1), dim3(1), 0, stream>>>(
      p_sum, lse2, counts, y + (size_t)T_TOK * HDIM);
}

// Round 6
// 533.341 us; speedup vs baseline: 1.0989x; 1.0496x over previous
//
#include <hip/hip_runtime.h>
#include <hip/hip_bf16.h>
#include <math.h>

// Problem constants (B,S,H,F,E,K) = (2,2048,1024,2048,8,2)
#define T_TOK 4096
#define HDIM  1024
#define FDIM  2048
#define EDIM  8
#define KSEL  2
#define TKROW 8192   // T*K
#define N2F   4096   // 2F
#define MAX_SLOTS 72 // = TK/128 + E = 72 ; also 72 = 8*9 exactly (clean XCD remap)

typedef __attribute__((ext_vector_type(8))) short short8;
typedef __attribute__((ext_vector_type(4))) float f32x4;

__device__ __forceinline__ unsigned short f32_to_bf16(float f) {
  unsigned int u = __float_as_uint(f);
  u += 0x7FFFu + ((u >> 16) & 1u);   // round-to-nearest-even
  return (unsigned short)(u >> 16);
}

// async global -> LDS, 16B per lane. LDS dest must be wave-uniform base + lane*16.
__device__ __forceinline__ void gload16(const void* g, void* l) {
  __builtin_amdgcn_global_load_lds(
      (const __attribute__((address_space(1))) unsigned int*)g,
      (__attribute__((address_space(3))) unsigned int*)l, 16, 0, 0);
}

// ---------------- conversion kernels ----------------

// in: [z][R][C] fp32 row-major; out: [z][C][R] bf16 row-major (transposed)
// write phase uses ushort2 (4B/lane) stores.
__global__ void transpose_conv_kernel(const float* __restrict__ in,
                                      unsigned short* __restrict__ out,
                                      int R, int C) {
  __shared__ float tile[64][65];
  long base = (long)blockIdx.z * (long)R * (long)C;
  int c0 = blockIdx.x * 64, r0 = blockIdx.y * 64;
  int tx = threadIdx.x & 63;   // contiguous dim
  int ty = threadIdx.x >> 6;   // 0..3
  #pragma unroll
  for (int j = 0; j < 64; j += 4) {
    int r = r0 + ty + j;
    tile[ty + j][tx] = in[base + (long)r * C + c0 + tx];
  }
  __syncthreads();
  int ow = threadIdx.x & 31;    // ushort2 index along R (covers 64 elems)
  int ocg = threadIdx.x >> 5;   // 0..7
  #pragma unroll
  for (int j = 0; j < 64; j += 8) {
    int oc = ocg + j;           // output row = c0+oc ; output col pair = r0+2*ow
    ushort2 o;
    o.x = f32_to_bf16(tile[2 * ow][oc]);
    o.y = f32_to_bf16(tile[2 * ow + 1][oc]);
    *(ushort2*)(out + base + (long)(c0 + oc) * R + r0 + 2 * ow) = o;
  }
}

// ---------------- router (fused: also emits xb bf16 copy of x) ----------------
__global__ void router_kernel(const float* __restrict__ x,
                              const float* __restrict__ wr,
                              unsigned short* __restrict__ xbout,
                              int* __restrict__ eid, float* __restrict__ tgate,
                              float* __restrict__ p_sum,
                              float* __restrict__ lse2_sum,
                              int* __restrict__ counts) {
  __shared__ float s_p[EDIM];
  __shared__ float s_lse2;
  __shared__ int s_cnt[EDIM];
  if (threadIdx.x < EDIM) { s_p[threadIdx.x] = 0.f; s_cnt[threadIdx.x] = 0; }
  if (threadIdx.x == 0) s_lse2 = 0.f;
  __syncthreads();

  int wave = threadIdx.x >> 6;
  int lane = threadIdx.x & 63;

  for (int it = 0; it < 4; ++it) {
    int t = (blockIdx.x * 4 + wave) + it * 1024;
    float acc[EDIM];
    #pragma unroll
    for (int e = 0; e < EDIM; e++) acc[e] = 0.f;
    const float* xr = x + (long)t * HDIM;
    unsigned short* xo = xbout + (long)t * HDIM;
    #pragma unroll
    for (int c = 0; c < 4; ++c) {
      int h0 = lane * 4 + c * 256;
      float4 v = *(const float4*)(xr + h0);
      ushort4 o;
      o.x = f32_to_bf16(v.x); o.y = f32_to_bf16(v.y);
      o.z = f32_to_bf16(v.z); o.w = f32_to_bf16(v.w);
      *(ushort4*)(xo + h0) = o;
      const float* w0 = wr + (long)h0 * EDIM;
      #pragma unroll
      for (int e = 0; e < EDIM; e++)
        acc[e] += v.x * w0[e] + v.y * w0[EDIM + e] +
                  v.z * w0[2 * EDIM + e] + v.w * w0[3 * EDIM + e];
    }
    #pragma unroll
    for (int e = 0; e < EDIM; e++) {
      float v = acc[e];
      for (int off = 32; off > 0; off >>= 1) v += __shfl_down(v, off);
      acc[e] = v;
    }
    if (lane == 0) {
      float m = acc[0];
      #pragma unroll
      for (int e = 1; e < EDIM; e++) m = fmaxf(m, acc[e]);
      float ex[EDIM]; float se = 0.f;
      #pragma unroll
      for (int e = 0; e < EDIM; e++) { ex[e] = __expf(acc[e] - m); se += ex[e]; }
      float lse = m + __logf(se);
      atomicAdd(&s_lse2, lse * lse);
      float inv = 1.f / se;
      #pragma unroll
      for (int e = 0; e < EDIM; e++) atomicAdd(&s_p[e], ex[e] * inv);
      int i1 = 0;
      #pragma unroll
      for (int e = 1; e < EDIM; e++) if (acc[e] > acc[i1]) i1 = e;
      int i2 = (i1 == 0) ? 1 : 0;
      #pragma unroll
      for (int e = 0; e < EDIM; e++) if (e != i1 && acc[e] > acc[i2]) i2 = e;
      float g1 = 1.f / (1.f + __expf(acc[i2] - acc[i1]));
      eid[t * 2] = i1; eid[t * 2 + 1] = i2;
      tgate[t * 2] = g1; tgate[t * 2 + 1] = 1.f - g1;
      atomicAdd(&s_cnt[i1], 1); atomicAdd(&s_cnt[i2], 1);
    }
  }
  __syncthreads();
  if (threadIdx.x < EDIM) {
    atomicAdd(&p_sum[threadIdx.x], s_p[threadIdx.x]);
    atomicAdd(&counts[threadIdx.x], s_cnt[threadIdx.x]);
  }
  if (threadIdx.x == 0) atomicAdd(lse2_sum, s_lse2);
}

// ---------------- scan (1 thread) — 128-row slots ----------------
__global__ void scan_kernel(const int* __restrict__ counts,
                            int* __restrict__ offsets, int* __restrict__ slot_e,
                            int* __restrict__ slot_m0, int* __restrict__ slot_rows,
                            int* __restrict__ n_slots, int* __restrict__ cursors) {
  int off = 0, s = 0;
  for (int e = 0; e < EDIM; e++) {
    offsets[e] = off;
    cursors[e] = 0;
    int c = counts[e];
    for (int m0 = 0; m0 < c; m0 += 128) {
      slot_e[s] = e; slot_m0[s] = off + m0;
      slot_rows[s] = min(128, c - m0); s++;
    }
    off += c;
  }
  *n_slots = s;
}

// ---------------- scatter (block-aggregated, records positions) ----------------
__global__ void scatter_kernel(const int* __restrict__ eid,
                               const float* __restrict__ tgate,
                               const int* __restrict__ offsets,
                               int* __restrict__ cursors,
                               int* __restrict__ btok, float* __restrict__ bgate,
                               int* __restrict__ tpos) {
  __shared__ int lcnt[EDIM];
  __shared__ int lbase[EDIM];
  int tid = threadIdx.x;
  if (tid < EDIM) lcnt[tid] = 0;
  __syncthreads();
  int t = blockIdx.x * 256 + tid;
  int e0 = eid[t * 2], e1 = eid[t * 2 + 1];
  int p0 = atomicAdd(&lcnt[e0], 1);
  int p1 = atomicAdd(&lcnt[e1], 1);
  __syncthreads();
  if (tid < EDIM) lbase[tid] = atomicAdd(&cursors[tid], lcnt[tid]);
  __syncthreads();
  int r0 = offsets[e0] + lbase[e0] + p0;
  int r1 = offsets[e1] + lbase[e1] + p1;
  btok[r0] = t; bgate[r0] = tgate[t * 2];     tpos[t * 2] = r0;
  btok[r1] = t; bgate[r1] = tgate[t * 2 + 1]; tpos[t * 2 + 1] = r1;
}

// ---------------- GEMM1: glu = GLU(X_bucket @ w_in[e]) ----------------
// Round-2 geometry (128 rows x 64 glu-cols, BK=64, 4 waves 2x2) with the
// minimal 2-phase pipeline: STAGE(next-buf) -> COMPUTE(cur-buf) -> barrier.
// One __syncthreads per K-step (vs 2 in round-2); drain overlaps compute.
// Static buffer names via 2x-unrolled body (no runtime cur index).
__global__ __launch_bounds__(256) void gemm1_kernel(
    const unsigned short* __restrict__ xb,      // [T][H] bf16
    const unsigned short* __restrict__ w_inT,   // [E][2F][H] bf16 (transposed)
    const int* __restrict__ btok,
    const int* __restrict__ slot_e, const int* __restrict__ slot_m0,
    const int* __restrict__ slot_rows, const int* __restrict__ n_slots,
    unsigned short* __restrict__ glu)           // [TK][F] bf16
{
  int bx = blockIdx.x;
  int slot = (bx & 7) * 9 + (bx >> 3);          // XCD-cluster: same-expert slots -> same XCD
  if (slot >= *n_slots) return;
  int e = slot_e[slot], r0 = slot_m0[slot], nrows = slot_rows[slot];
  int by = blockIdx.y;                          // 0..31 (64 glu cols per block)

  __shared__ unsigned short lA[2][128 * 64];    // 2 x 16 KiB, linear (gload dest)
  __shared__ unsigned short lB[2][128 * 64];

  int tid = threadIdx.x;
  int lane = tid & 63, wv = tid >> 6;
  int wr = wv >> 1, wc = wv & 1;
  int lm = lane & 15, lq = lane >> 4, l7 = lane & 7;

  // staging: thread covers chunks ci = tid + i*256 ; row=ci>>3, kc_dest=ci&7
  // source is pre-swizzled: kc_src = kc_dest ^ (row&7)  (both-sides involution)
  int srow = tid >> 3, skc = tid & 7;
  const unsigned short* asrc[4];
  const unsigned short* bsrc[4];
  #pragma unroll
  for (int i = 0; i < 4; ++i) {
    int row = srow + i * 32;
    int swz = (skc ^ (row & 7)) * 8;            // bf16 elems
    int ar = min(row, nrows - 1);               // clamp: garbage rows masked at store
    int tok = btok[r0 + ar];
    asrc[i] = xb + (long)tok * HDIM + swz;
    // B row n -> w_inT row: per-32 interleave [a0-31][g0-31][a32-63][g32-63]
    int group = row >> 5, within = row & 31;
    int bcol = by * 64 + (group >> 1) * 32 + within + ((group & 1) ? FDIM : 0);
    bsrc[i] = w_inT + ((long)e * N2F + bcol) * HDIM + swz;
  }

  f32x4 acc[4][4];
  #pragma unroll
  for (int mf = 0; mf < 4; ++mf)
    #pragma unroll
    for (int nf = 0; nf < 4; ++nf) acc[mf][nf] = (f32x4){0.f, 0.f, 0.f, 0.f};

  auto stage = [&](unsigned short* dA, unsigned short* dB, int k0) {
    #pragma unroll
    for (int i = 0; i < 4; ++i) {
      gload16(asrc[i] + k0, dA + tid * 8 + i * 2048);
      gload16(bsrc[i] + k0, dB + tid * 8 + i * 2048);
    }
  };
  auto compute = [&](const unsigned short* cA, const unsigned short* cB) {
    #pragma unroll
    for (int ks = 0; ks < 2; ++ks) {
      short8 a[4], b[4];
      #pragma unroll
      for (int mf = 0; mf < 4; ++mf) {
        int row = wr * 64 + mf * 16 + lm;
        a[mf] = *(const short8*)&cA[row * 64 + (((ks * 4 + lq) ^ l7) * 8)];
      }
      #pragma unroll
      for (int nf = 0; nf < 4; ++nf) {
        int n = wc * 64 + nf * 16 + lm;
        b[nf] = *(const short8*)&cB[n * 64 + (((ks * 4 + lq) ^ l7) * 8)];
      }
      #pragma unroll
      for (int mf = 0; mf < 4; ++mf)
        #pragma unroll
        for (int nf = 0; nf < 4; ++nf)
          acc[mf][nf] = __builtin_amdgcn_mfma_f32_16x16x32_bf16(a[mf], b[nf], acc[mf][nf], 0, 0, 0);
    }
  };

  stage(&lA[0][0], &lB[0][0], 0);
  __syncthreads();                       // buf0 tile-0 ready
  const int NIT = HDIM / 64;             // 16 (even)
  for (int it = 0; it < NIT; it += 2) {
    if (it + 1 < NIT) stage(&lA[1][0], &lB[1][0], (it + 1) * 64);
    compute(&lA[0][0], &lB[0][0]);
    __syncthreads();                     // buf0 reads done + buf1 loads drained
    if (it + 2 < NIT) stage(&lA[0][0], &lB[0][0], (it + 2) * 64);
    compute(&lA[1][0], &lB[1][0]);
    __syncthreads();                     // buf1 reads done + buf0 loads drained
  }

  // epilogue: GLU pair: a = acc[mf][nf], g = acc[mf][nf+2]  (nf in {0,1})
  // output col = by*64 + wc*32 + nf*16 + lm
  #pragma unroll
  for (int mf = 0; mf < 4; ++mf) {
    #pragma unroll
    for (int r = 0; r < 4; ++r) {
      int row = wr * 64 + mf * 16 + lq * 4 + r;
      if (row < nrows) {
        #pragma unroll
        for (int nf = 0; nf < 2; ++nf) {
          float a = acc[mf][nf][r];
          float g = acc[mf][nf + 2][r];
          float val = (a / (1.f + __expf(-a))) * g;   // silu(a)*g
          glu[(long)(r0 + row) * FDIM + by * 64 + wc * 32 + nf * 16 + lm] = f32_to_bf16(val);
        }
      }
    }
  }
}

// ---------------- GEMM2: out_rows = gate * (glu @ w_out[e]) ----------------
// 128x128 tile, K=2048, same minimal 2-phase pipeline, plain stores.
__global__ __launch_bounds__(256) void gemm2_kernel(
    const unsigned short* __restrict__ glu,     // [TK][F] bf16 (bucket order)
    const unsigned short* __restrict__ w_outT,  // [E][H][F] bf16 (transposed)
    const float* __restrict__ bgate,
    const int* __restrict__ slot_e, const int* __restrict__ slot_m0,
    const int* __restrict__ slot_rows, const int* __restrict__ n_slots,
    float* __restrict__ orows)                  // [TK][H] fp32
{
  int bx = blockIdx.x;
  int slot = (bx & 7) * 9 + (bx >> 3);
  if (slot >= *n_slots) return;
  int e = slot_e[slot], r0 = slot_m0[slot], nrows = slot_rows[slot];
  int c0 = blockIdx.y * 128;                    // 0..7 blocks

  __shared__ unsigned short lA[2][128 * 64];
  __shared__ unsigned short lB[2][128 * 64];

  int tid = threadIdx.x;
  int lane = tid & 63, wv = tid >> 6;
  int wr = wv >> 1, wc = wv & 1;
  int lm = lane & 15, lq = lane >> 4, l7 = lane & 7;

  int srow = tid >> 3, skc = tid & 7;
  const unsigned short* asrc[4];
  const unsigned short* bsrc[4];
  #pragma unroll
  for (int i = 0; i < 4; ++i) {
    int row = srow + i * 32;
    int swz = (skc ^ (row & 7)) * 8;
    int ar = min(row, nrows - 1);
    asrc[i] = glu + (long)(r0 + ar) * FDIM + swz;
    bsrc[i] = w_outT + ((long)e * HDIM + c0 + row) * FDIM + swz;
  }

  f32x4 acc[4][4];
  #pragma unroll
  for (int mf = 0; mf < 4; ++mf)
    #pragma unroll
    for (int nf = 0; nf < 4; ++nf) acc[mf][nf] = (f32x4){0.f, 0.f, 0.f, 0.f};

  auto stage = [&](unsigned short* dA, unsigned short* dB, int k0) {
    #pragma unroll
    for (int i = 0; i < 4; ++i) {
      gload16(asrc[i] + k0, dA + tid * 8 + i * 2048);
      gload16(bsrc[i] + k0, dB + tid * 8 + i * 2048);
    }
  };
  auto compute = [&](const unsigned short* cA, const unsigned short* cB) {
    #pragma unroll
    for (int ks = 0; ks < 2; ++ks) {
      short8 a[4], b[4];
      #pragma unroll
      for (int mf = 0; mf < 4; ++mf) {
        int row = wr * 64 + mf * 16 + lm;
        a[mf] = *(const short8*)&cA[row * 64 + (((ks * 4 + lq) ^ l7) * 8)];
      }
      #pragma unroll
      for (int nf = 0; nf < 4; ++nf) {
        int n = wc * 64 + nf * 16 + lm;
        b[nf] = *(const short8*)&cB[n * 64 + (((ks * 4 + lq) ^ l7) * 8)];
      }
      #pragma unroll
      for (int mf = 0; mf < 4; ++mf)
        #pragma unroll
        for (int nf = 0; nf < 4; ++nf)
          acc[mf][nf] = __builtin_amdgcn_mfma_f32_16x16x32_bf16(a[mf], b[nf], acc[mf][nf], 0, 0, 0);
    }
  };

  stage(&lA[0][0], &lB[0][0], 0);
  __syncthreads();
  const int NIT = FDIM / 64;             // 32 (even)
  for (int it = 0; it < NIT; it += 2) {
    if (it + 1 < NIT) stage(&lA[1][0], &lB[1][0], (it + 1) * 64);
    compute(&lA[0][0], &lB[0][0]);
    __syncthreads();
    if (it + 2 < NIT) stage(&lA[0][0], &lB[0][0], (it + 2) * 64);
    compute(&lA[1][0], &lB[1][0]);
    __syncthreads();
  }

  #pragma unroll
  for (int mf = 0; mf < 4; ++mf) {
    #pragma unroll
    for (int r = 0; r < 4; ++r) {
      int row = wr * 64 + mf * 16 + lq * 4 + r;
      if (row < nrows) {
        float g = bgate[r0 + row];
        #pragma unroll
        for (int nf = 0; nf < 4; ++nf) {
          orows[(long)(r0 + row) * HDIM + c0 + wc * 64 + nf * 16 + lm] = acc[mf][nf][r] * g;
        }
      }
    }
  }
}

// ---------------- combine: y[t] = bias + orows[pos0] + orows[pos1] ----------------
__global__ void combine_kernel(const float* __restrict__ orows,
                               const int* __restrict__ tpos,
                               const float* __restrict__ bias,
                               float* __restrict__ y) {
  int i = blockIdx.x * 256 + threadIdx.x;   // over T*H/4
  int t = i >> 8;                            // HDIM/4 = 256 float4 per token
  int h = (i & 255) * 4;
  int p0 = tpos[t * 2], p1 = tpos[t * 2 + 1];
  float4 a = *(const float4*)(orows + (long)p0 * HDIM + h);
  float4 b = *(const float4*)(orows + (long)p1 * HDIM + h);
  float4 bv = *(const float4*)(bias + h);
  float4 o;
  o.x = a.x + b.x + bv.x; o.y = a.y + b.y + bv.y;
  o.z = a.z + b.z + bv.z; o.w = a.w + b.w + bv.w;
  *(float4*)(y + (long)t * HDIM + h) = o;
}

// ---------------- finalize loss ----------------
__global__ void finalize_kernel(const float* __restrict__ p_sum,
                                const float* __restrict__ lse2,
                                const int* __restrict__ counts,
                                float* __restrict__ loss_out) {
  float P = 0.f;
  for (int e = 0; e < EDIM; e++) P += p_sum[e];
  float dot = 0.f;
  for (int e = 0; e < EDIM; e++)
    dot += (p_sum[e] / P) * ((float)counts[e] / (float)TKROW);
  *loss_out = (float)EDIM * dot + 0.1f * (*lse2) / (float)T_TOK;
}

// ---------------- host launch ----------------
extern "C" void kernel_launch(void* const* d_in, const int* in_sizes, int n_in,
                              void* d_out, int out_size, void* d_ws, size_t ws_size,
                              hipStream_t stream) {
  const float* x        = (const float*)d_in[0];
  const float* w_router = (const float*)d_in[1];
  const float* w_in     = (const float*)d_in[2];
  const float* w_out    = (const float*)d_in[3];
  const float* bias     = (const float*)d_in[4];
  float* y = (float*)d_out;                  // [T*H] then loss at [T*H]

  char* ws = (char*)d_ws;
  size_t o = 0;
  auto alloc = [&](size_t bytes) { size_t r = o; o = (o + bytes + 255) & ~(size_t)255; return r; };
  size_t o_meta    = alloc(256);              // p_sum[8],lse2,counts[8],cursors[8],n_slots
  size_t o_offsets = alloc(EDIM * 4);
  size_t o_slot_e  = alloc(MAX_SLOTS * 4);
  size_t o_slot_m0 = alloc(MAX_SLOTS * 4);
  size_t o_slot_nr = alloc(MAX_SLOTS * 4);
  size_t o_eid     = alloc((size_t)T_TOK * 2 * 4);
  size_t o_tgate   = alloc((size_t)T_TOK * 2 * 4);
  size_t o_tpos    = alloc((size_t)T_TOK * 2 * 4);
  size_t o_btok    = alloc((size_t)TKROW * 4);
  size_t o_bgate   = alloc((size_t)TKROW * 4);
  size_t o_xb      = alloc((size_t)T_TOK * HDIM * 2);
  size_t o_winT    = alloc((size_t)EDIM * N2F * HDIM * 2);  // 64 MiB
  size_t o_woutT   = alloc((size_t)EDIM * HDIM * FDIM * 2); // 32 MiB
  size_t o_glu     = alloc((size_t)TKROW * FDIM * 2);       // 32 MiB
  // orows (32 MiB) ALIASES winT: winT is dead after gemm1, orows is written by
  // gemm2 and read by combine, both strictly later in stream order. Keeps the
  // total workspace footprint at the proven-safe ~136.5 MiB (round-0 size).
  size_t o_orows   = o_winT;
  (void)ws_size;

  float* p_sum   = (float*)(ws + o_meta);
  float* lse2    = (float*)(ws + o_meta + 32);
  int*   counts  = (int*)(ws + o_meta + 64);
  int*   cursors = (int*)(ws + o_meta + 96);
  int*   n_slots = (int*)(ws + o_meta + 128);
  int*   offsets = (int*)(ws + o_offsets);
  int*   slot_e  = (int*)(ws + o_slot_e);
  int*   slot_m0 = (int*)(ws + o_slot_m0);
  int*   slot_nr = (int*)(ws + o_slot_nr);
  int*   eid     = (int*)(ws + o_eid);
  float* tgate   = (float*)(ws + o_tgate);
  int*   tpos    = (int*)(ws + o_tpos);
  int*   btok    = (int*)(ws + o_btok);
  float* bgate   = (float*)(ws + o_bgate);
  unsigned short* xb    = (unsigned short*)(ws + o_xb);
  unsigned short* winT  = (unsigned short*)(ws + o_winT);
  unsigned short* woutT = (unsigned short*)(ws + o_woutT);
  unsigned short* glu   = (unsigned short*)(ws + o_glu);
  float* orows = (float*)(ws + o_orows);

  hipMemsetAsync(ws, 0, 256, stream);

  // weight conversions
  transpose_conv_kernel<<<dim3(N2F / 64, HDIM / 64, EDIM), dim3(256), 0, stream>>>(
      w_in, winT, HDIM, N2F);
  transpose_conv_kernel<<<dim3(HDIM / 64, FDIM / 64, EDIM), dim3(256), 0, stream>>>(
      w_out, woutT, FDIM, HDIM);

  // routing (also produces xb, the bf16 copy of x)
  router_kernel<<<dim3(256), dim3(256), 0, stream>>>(
      x, w_router, xb, eid, tgate, p_sum, lse2, counts);
  scan_kernel<<<dim3(1), dim3(1), 0, stream>>>(
      counts, offsets, slot_e, slot_m0, slot_nr, n_slots, cursors);
  scatter_kernel<<<dim3(T_TOK / 256), dim3(256), 0, stream>>>(
      eid, tgate, offsets, cursors, btok, bgate, tpos);

  // expert GEMMs (gemm1 reads winT; gemm2 then overwrites that region as orows)
  gemm1_kernel<<<dim3(MAX_SLOTS, FDIM / 64), dim3(256), 0, stream>>>(
      xb, winT, btok, slot_e, slot_m0, slot_nr, n_slots, glu);
  gemm2_kernel<<<dim3(MAX_SLOTS, HDIM / 128), dim3(256), 0, stream>>>(
      glu, woutT, bgate, slot_e, slot_m0, slot_nr, n_slots, orows);

  // combine + loss
  combine_kernel<<<dim3((T_TOK * HDIM) / 1024), dim3(256), 0, stream>>>(
      orows, tpos, bias, y);
  finalize_kernel<<<dim3(1), dim3(1), 0, stream>>>(
      p_sum, lse2, counts, y + (size_t)T_TOK * HDIM);
}

// Round 7
// 496.434 us; speedup vs baseline: 1.1806x; 1.0743x over previous
//
#include <hip/hip_runtime.h>
#include <hip/hip_bf16.h>
#include <math.h>

// Problem constants (B,S,H,F,E,K) = (2,2048,1024,2048,8,2)
#define T_TOK 4096
#define HDIM  1024
#define FDIM  2048
#define EDIM  8
#define KSEL  2
#define TKROW 8192   // T*K
#define N2F   4096   // 2F
#define MAX_SLOTS  72  // 128-row slots: TK/128 + E = 72 = 8*9 (clean XCD remap)
#define MAX_SLOTS2 136 // 64-row slots:  TK/64  + E = 136 = 8*17

typedef __attribute__((ext_vector_type(8))) short short8;
typedef __attribute__((ext_vector_type(4))) float f32x4;

__device__ __forceinline__ unsigned short f32_to_bf16(float f) {
  unsigned int u = __float_as_uint(f);
  u += 0x7FFFu + ((u >> 16) & 1u);   // round-to-nearest-even
  return (unsigned short)(u >> 16);
}

// async global -> LDS, 16B per lane. LDS dest must be wave-uniform base + lane*16.
__device__ __forceinline__ void gload16(const void* g, void* l) {
  __builtin_amdgcn_global_load_lds(
      (const __attribute__((address_space(1))) unsigned int*)g,
      (__attribute__((address_space(3))) unsigned int*)l, 16, 0, 0);
}

// ---------------- conversion kernels ----------------

// in: [z][R][C] fp32 row-major; out: [z][C][R] bf16 row-major (transposed)
// write phase uses ushort2 (4B/lane) stores.
__global__ void transpose_conv_kernel(const float* __restrict__ in,
                                      unsigned short* __restrict__ out,
                                      int R, int C) {
  __shared__ float tile[64][65];
  long base = (long)blockIdx.z * (long)R * (long)C;
  int c0 = blockIdx.x * 64, r0 = blockIdx.y * 64;
  int tx = threadIdx.x & 63;   // contiguous dim
  int ty = threadIdx.x >> 6;   // 0..3
  #pragma unroll
  for (int j = 0; j < 64; j += 4) {
    int r = r0 + ty + j;
    tile[ty + j][tx] = in[base + (long)r * C + c0 + tx];
  }
  __syncthreads();
  int ow = threadIdx.x & 31;    // ushort2 index along R (covers 64 elems)
  int ocg = threadIdx.x >> 5;   // 0..7
  #pragma unroll
  for (int j = 0; j < 64; j += 8) {
    int oc = ocg + j;           // output row = c0+oc ; output col pair = r0+2*ow
    ushort2 o;
    o.x = f32_to_bf16(tile[2 * ow][oc]);
    o.y = f32_to_bf16(tile[2 * ow + 1][oc]);
    *(ushort2*)(out + base + (long)(c0 + oc) * R + r0 + 2 * ow) = o;
  }
}

// ---------------- router (fused: also emits xb bf16 copy of x) ----------------
__global__ void router_kernel(const float* __restrict__ x,
                              const float* __restrict__ wr,
                              unsigned short* __restrict__ xbout,
                              int* __restrict__ eid, float* __restrict__ tgate,
                              float* __restrict__ p_sum,
                              float* __restrict__ lse2_sum,
                              int* __restrict__ counts) {
  __shared__ float s_p[EDIM];
  __shared__ float s_lse2;
  __shared__ int s_cnt[EDIM];
  if (threadIdx.x < EDIM) { s_p[threadIdx.x] = 0.f; s_cnt[threadIdx.x] = 0; }
  if (threadIdx.x == 0) s_lse2 = 0.f;
  __syncthreads();

  int wave = threadIdx.x >> 6;
  int lane = threadIdx.x & 63;

  for (int it = 0; it < 4; ++it) {
    int t = (blockIdx.x * 4 + wave) + it * 1024;
    float acc[EDIM];
    #pragma unroll
    for (int e = 0; e < EDIM; e++) acc[e] = 0.f;
    const float* xr = x + (long)t * HDIM;
    unsigned short* xo = xbout + (long)t * HDIM;
    #pragma unroll
    for (int c = 0; c < 4; ++c) {
      int h0 = lane * 4 + c * 256;
      float4 v = *(const float4*)(xr + h0);
      ushort4 o;
      o.x = f32_to_bf16(v.x); o.y = f32_to_bf16(v.y);
      o.z = f32_to_bf16(v.z); o.w = f32_to_bf16(v.w);
      *(ushort4*)(xo + h0) = o;
      const float* w0 = wr + (long)h0 * EDIM;
      #pragma unroll
      for (int e = 0; e < EDIM; e++)
        acc[e] += v.x * w0[e] + v.y * w0[EDIM + e] +
                  v.z * w0[2 * EDIM + e] + v.w * w0[3 * EDIM + e];
    }
    #pragma unroll
    for (int e = 0; e < EDIM; e++) {
      float v = acc[e];
      for (int off = 32; off > 0; off >>= 1) v += __shfl_down(v, off);
      acc[e] = v;
    }
    if (lane == 0) {
      float m = acc[0];
      #pragma unroll
      for (int e = 1; e < EDIM; e++) m = fmaxf(m, acc[e]);
      float ex[EDIM]; float se = 0.f;
      #pragma unroll
      for (int e = 0; e < EDIM; e++) { ex[e] = __expf(acc[e] - m); se += ex[e]; }
      float lse = m + __logf(se);
      atomicAdd(&s_lse2, lse * lse);
      float inv = 1.f / se;
      #pragma unroll
      for (int e = 0; e < EDIM; e++) atomicAdd(&s_p[e], ex[e] * inv);
      int i1 = 0;
      #pragma unroll
      for (int e = 1; e < EDIM; e++) if (acc[e] > acc[i1]) i1 = e;
      int i2 = (i1 == 0) ? 1 : 0;
      #pragma unroll
      for (int e = 0; e < EDIM; e++) if (e != i1 && acc[e] > acc[i2]) i2 = e;
      float g1 = 1.f / (1.f + __expf(acc[i2] - acc[i1]));
      eid[t * 2] = i1; eid[t * 2 + 1] = i2;
      tgate[t * 2] = g1; tgate[t * 2 + 1] = 1.f - g1;
      atomicAdd(&s_cnt[i1], 1); atomicAdd(&s_cnt[i2], 1);
    }
  }
  __syncthreads();
  if (threadIdx.x < EDIM) {
    atomicAdd(&p_sum[threadIdx.x], s_p[threadIdx.x]);
    atomicAdd(&counts[threadIdx.x], s_cnt[threadIdx.x]);
  }
  if (threadIdx.x == 0) atomicAdd(lse2_sum, s_lse2);
}

// ---------------- scan (parallelized): emits 128-row AND 64-row slot lists ----
__global__ void scan_kernel(const int* __restrict__ counts,
                            int* __restrict__ offsets,
                            int* __restrict__ slot_e, int* __restrict__ slot_m0,
                            int* __restrict__ slot_rows, int* __restrict__ n_slots,
                            int* __restrict__ slot2_e, int* __restrict__ slot2_m0,
                            int* __restrict__ slot2_rows, int* __restrict__ n_slots2,
                            int* __restrict__ cursors) {
  __shared__ int s_cnt[EDIM], s_off[EDIM], s_b1[EDIM], s_b2[EDIM];
  __shared__ int s_ns1, s_ns2;
  int tid = threadIdx.x;
  if (tid < EDIM) s_cnt[tid] = counts[tid];
  __syncthreads();
  if (tid == 0) {
    int off = 0, s1 = 0, s2 = 0;
    for (int e = 0; e < EDIM; e++) {
      s_off[e] = off; s_b1[e] = s1; s_b2[e] = s2;
      int c = s_cnt[e];
      s1 += (c + 127) >> 7;
      s2 += (c + 63) >> 6;
      off += c;
    }
    s_ns1 = s1; s_ns2 = s2;
  }
  __syncthreads();
  if (tid < EDIM) { offsets[tid] = s_off[tid]; cursors[tid] = 0; }
  if (tid == 0) { *n_slots = s_ns1; *n_slots2 = s_ns2; }
  // parallel slot emission
  for (int e = 0; e < EDIM; e++) {
    int c = s_cnt[e], off = s_off[e];
    int n1 = (c + 127) >> 7, n2 = (c + 63) >> 6;
    for (int i = tid; i < n1; i += 256) {
      int s = s_b1[e] + i;
      slot_e[s] = e; slot_m0[s] = off + i * 128;
      slot_rows[s] = min(128, c - i * 128);
    }
    for (int i = tid; i < n2; i += 256) {
      int s = s_b2[e] + i;
      slot2_e[s] = e; slot2_m0[s] = off + i * 64;
      slot2_rows[s] = min(64, c - i * 64);
    }
  }
}

// ---------------- scatter (block-aggregated, records positions) ----------------
__global__ void scatter_kernel(const int* __restrict__ eid,
                               const float* __restrict__ tgate,
                               const int* __restrict__ offsets,
                               int* __restrict__ cursors,
                               int* __restrict__ btok, float* __restrict__ bgate,
                               int* __restrict__ tpos) {
  __shared__ int lcnt[EDIM];
  __shared__ int lbase[EDIM];
  int tid = threadIdx.x;
  if (tid < EDIM) lcnt[tid] = 0;
  __syncthreads();
  int t = blockIdx.x * 256 + tid;
  int e0 = eid[t * 2], e1 = eid[t * 2 + 1];
  int p0 = atomicAdd(&lcnt[e0], 1);
  int p1 = atomicAdd(&lcnt[e1], 1);
  __syncthreads();
  if (tid < EDIM) lbase[tid] = atomicAdd(&cursors[tid], lcnt[tid]);
  __syncthreads();
  int r0 = offsets[e0] + lbase[e0] + p0;
  int r1 = offsets[e1] + lbase[e1] + p1;
  btok[r0] = t; bgate[r0] = tgate[t * 2];     tpos[t * 2] = r0;
  btok[r1] = t; bgate[r1] = tgate[t * 2 + 1]; tpos[t * 2 + 1] = r1;
}

// ---------------- GEMM1: glu = GLU(X_bucket @ w_in[e]) ----------------
// EXACT round-2 structure (proven 133 us): 128 rows x 64 glu-cols, BK=64,
// single LDS buffer, stage -> __syncthreads -> compute -> __syncthreads.
__global__ __launch_bounds__(256) void gemm1_kernel(
    const unsigned short* __restrict__ xb,      // [T][H] bf16
    const unsigned short* __restrict__ w_inT,   // [E][2F][H] bf16 (transposed)
    const int* __restrict__ btok,
    const int* __restrict__ slot_e, const int* __restrict__ slot_m0,
    const int* __restrict__ slot_rows, const int* __restrict__ n_slots,
    unsigned short* __restrict__ glu)           // [TK][F] bf16
{
  int bx = blockIdx.x;
  int slot = (bx & 7) * 9 + (bx >> 3);          // XCD-cluster: same-expert slots -> same XCD
  if (slot >= *n_slots) return;
  int e = slot_e[slot], r0 = slot_m0[slot], nrows = slot_rows[slot];
  int by = blockIdx.y;                          // 0..31 (64 glu cols per block)

  __shared__ unsigned short lA[128 * 64];       // 16 KiB, linear (gload dest)
  __shared__ unsigned short lB[128 * 64];       // 16 KiB

  int tid = threadIdx.x;
  int lane = tid & 63, wv = tid >> 6;
  int wr = wv >> 1, wc = wv & 1;
  int lm = lane & 15, lq = lane >> 4, l7 = lane & 7;

  // staging: thread covers chunks ci = tid + i*256 ; row=ci>>3, kc_dest=ci&7
  // source is pre-swizzled: kc_src = kc_dest ^ (row&7)  (both-sides involution)
  int srow = tid >> 3, skc = tid & 7;
  const unsigned short* asrc[4];
  const unsigned short* bsrc[4];
  #pragma unroll
  for (int i = 0; i < 4; ++i) {
    int row = srow + i * 32;
    int swz = (skc ^ (row & 7)) * 8;            // bf16 elems
    int ar = min(row, nrows - 1);               // clamp: garbage rows masked at store
    int tok = btok[r0 + ar];
    asrc[i] = xb + (long)tok * HDIM + swz;
    // B row n -> w_inT row: per-32 interleave [a0-31][g0-31][a32-63][g32-63]
    int group = row >> 5, within = row & 31;
    int bcol = by * 64 + (group >> 1) * 32 + within + ((group & 1) ? FDIM : 0);
    bsrc[i] = w_inT + ((long)e * N2F + bcol) * HDIM + swz;
  }

  f32x4 acc[4][4];
  #pragma unroll
  for (int mf = 0; mf < 4; ++mf)
    #pragma unroll
    for (int nf = 0; nf < 4; ++nf) acc[mf][nf] = (f32x4){0.f, 0.f, 0.f, 0.f};

  for (int k0 = 0; k0 < HDIM; k0 += 64) {
    #pragma unroll
    for (int i = 0; i < 4; ++i) {
      gload16(asrc[i] + k0, &lA[tid * 8 + i * 2048]);
      gload16(bsrc[i] + k0, &lB[tid * 8 + i * 2048]);
    }
    __syncthreads();   // compiler drains vmcnt before s_barrier
    #pragma unroll
    for (int ks = 0; ks < 2; ++ks) {
      short8 a[4], b[4];
      #pragma unroll
      for (int mf = 0; mf < 4; ++mf) {
        int row = wr * 64 + mf * 16 + lm;
        a[mf] = *(const short8*)&lA[row * 64 + (((ks * 4 + lq) ^ l7) * 8)];
      }
      #pragma unroll
      for (int nf = 0; nf < 4; ++nf) {
        int n = wc * 64 + nf * 16 + lm;
        b[nf] = *(const short8*)&lB[n * 64 + (((ks * 4 + lq) ^ l7) * 8)];
      }
      #pragma unroll
      for (int mf = 0; mf < 4; ++mf)
        #pragma unroll
        for (int nf = 0; nf < 4; ++nf)
          acc[mf][nf] = __builtin_amdgcn_mfma_f32_16x16x32_bf16(a[mf], b[nf], acc[mf][nf], 0, 0, 0);
    }
    __syncthreads();
  }

  // epilogue: GLU pair: a = acc[mf][nf], g = acc[mf][nf+2]  (nf in {0,1})
  // output col = by*64 + wc*32 + nf*16 + lm
  #pragma unroll
  for (int mf = 0; mf < 4; ++mf) {
    #pragma unroll
    for (int r = 0; r < 4; ++r) {
      int row = wr * 64 + mf * 16 + lq * 4 + r;
      if (row < nrows) {
        #pragma unroll
        for (int nf = 0; nf < 2; ++nf) {
          float a = acc[mf][nf][r];
          float g = acc[mf][nf + 2][r];
          float val = (a / (1.f + __expf(-a))) * g;   // silu(a)*g
          glu[(long)(r0 + row) * FDIM + by * 64 + wc * 32 + nf * 16 + lm] = f32_to_bf16(val);
        }
      }
    }
  }
}

// ---------------- GEMM2: out_rows = gate * (glu @ w_out[e]) ----------------
// 64-row slots x 128 cols, K=2048. Round-2 sync template; grid (136,8)=1088
// blocks (1.9x round-2's 576) to hide the per-K-step drain latency.
// LDS 24 KiB/block, acc[2][4] -> high residency.
__global__ __launch_bounds__(256) void gemm2_kernel(
    const unsigned short* __restrict__ glu,     // [TK][F] bf16 (bucket order)
    const unsigned short* __restrict__ w_outT,  // [E][H][F] bf16 (transposed)
    const float* __restrict__ bgate,
    const int* __restrict__ slot2_e, const int* __restrict__ slot2_m0,
    const int* __restrict__ slot2_rows, const int* __restrict__ n_slots2,
    float* __restrict__ orows)                  // [TK][H] fp32
{
  int bx = blockIdx.x;
  int slot = (bx & 7) * 17 + (bx >> 3);         // bijective over 136 = 8*17
  if (slot >= *n_slots2) return;
  int e = slot2_e[slot], r0 = slot2_m0[slot], nrows = slot2_rows[slot];
  int c0 = blockIdx.y * 128;                    // 0..7 blocks

  __shared__ unsigned short lA[64 * 64];        // 8 KiB
  __shared__ unsigned short lB[128 * 64];       // 16 KiB

  int tid = threadIdx.x;
  int lane = tid & 63, wv = tid >> 6;
  int wr = wv >> 1, wc = wv & 1;
  int lm = lane & 15, lq = lane >> 4, l7 = lane & 7;

  int srow = tid >> 3, skc = tid & 7;
  const unsigned short* asrc[2];
  const unsigned short* bsrc[4];
  #pragma unroll
  for (int i = 0; i < 2; ++i) {
    int row = srow + i * 32;                    // 0..63
    int swz = (skc ^ (row & 7)) * 8;
    int ar = min(row, nrows - 1);
    asrc[i] = glu + (long)(r0 + ar) * FDIM + swz;
  }
  #pragma unroll
  for (int i = 0; i < 4; ++i) {
    int row = srow + i * 32;                    // 0..127
    int swz = (skc ^ (row & 7)) * 8;
    bsrc[i] = w_outT + ((long)e * HDIM + c0 + row) * FDIM + swz;
  }

  f32x4 acc[2][4];
  #pragma unroll
  for (int mf = 0; mf < 2; ++mf)
    #pragma unroll
    for (int nf = 0; nf < 4; ++nf) acc[mf][nf] = (f32x4){0.f, 0.f, 0.f, 0.f};

  for (int k0 = 0; k0 < FDIM; k0 += 64) {
    #pragma unroll
    for (int i = 0; i < 2; ++i) gload16(asrc[i] + k0, &lA[tid * 8 + i * 2048]);
    #pragma unroll
    for (int i = 0; i < 4; ++i) gload16(bsrc[i] + k0, &lB[tid * 8 + i * 2048]);
    __syncthreads();
    #pragma unroll
    for (int ks = 0; ks < 2; ++ks) {
      short8 a[2], b[4];
      #pragma unroll
      for (int mf = 0; mf < 2; ++mf) {
        int row = wr * 32 + mf * 16 + lm;       // 0..63
        a[mf] = *(const short8*)&lA[row * 64 + (((ks * 4 + lq) ^ l7) * 8)];
      }
      #pragma unroll
      for (int nf = 0; nf < 4; ++nf) {
        int n = wc * 64 + nf * 16 + lm;         // 0..127
        b[nf] = *(const short8*)&lB[n * 64 + (((ks * 4 + lq) ^ l7) * 8)];
      }
      #pragma unroll
      for (int mf = 0; mf < 2; ++mf)
        #pragma unroll
        for (int nf = 0; nf < 4; ++nf)
          acc[mf][nf] = __builtin_amdgcn_mfma_f32_16x16x32_bf16(a[mf], b[nf], acc[mf][nf], 0, 0, 0);
    }
    __syncthreads();
  }

  #pragma unroll
  for (int mf = 0; mf < 2; ++mf) {
    #pragma unroll
    for (int r = 0; r < 4; ++r) {
      int row = wr * 32 + mf * 16 + lq * 4 + r;
      if (row < nrows) {
        float g = bgate[r0 + row];
        #pragma unroll
        for (int nf = 0; nf < 4; ++nf) {
          orows[(long)(r0 + row) * HDIM + c0 + wc * 64 + nf * 16 + lm] = acc[mf][nf][r] * g;
        }
      }
    }
  }
}

// ---------------- combine: y[t] = bias + orows[pos0] + orows[pos1] ----------------
__global__ void combine_kernel(const float* __restrict__ orows,
                               const int* __restrict__ tpos,
                               const float* __restrict__ bias,
                               float* __restrict__ y) {
  int i = blockIdx.x * 256 + threadIdx.x;   // over T*H/4
  int t = i >> 8;                            // HDIM/4 = 256 float4 per token
  int h = (i & 255) * 4;
  int p0 = tpos[t * 2], p1 = tpos[t * 2 + 1];
  float4 a = *(const float4*)(orows + (long)p0 * HDIM + h);
  float4 b = *(const float4*)(orows + (long)p1 * HDIM + h);
  float4 bv = *(const float4*)(bias + h);
  float4 o;
  o.x = a.x + b.x + bv.x; o.y = a.y + b.y + bv.y;
  o.z = a.z + b.z + bv.z; o.w = a.w + b.w + bv.w;
  *(float4*)(y + (long)t * HDIM + h) = o;
}

// ---------------- finalize loss ----------------
__global__ void finalize_kernel(const float* __restrict__ p_sum,
                                const float* __restrict__ lse2,
                                const int* __restrict__ counts,
                                float* __restrict__ loss_out) {
  float P = 0.f;
  for (int e = 0; e < EDIM; e++) P += p_sum[e];
  float dot = 0.f;
  for (int e = 0; e < EDIM; e++)
    dot += (p_sum[e] / P) * ((float)counts[e] / (float)TKROW);
  *loss_out = (float)EDIM * dot + 0.1f * (*lse2) / (float)T_TOK;
}

// ---------------- host launch ----------------
extern "C" void kernel_launch(void* const* d_in, const int* in_sizes, int n_in,
                              void* d_out, int out_size, void* d_ws, size_t ws_size,
                              hipStream_t stream) {
  const float* x        = (const float*)d_in[0];
  const float* w_router = (const float*)d_in[1];
  const float* w_in     = (const float*)d_in[2];
  const float* w_out    = (const float*)d_in[3];
  const float* bias     = (const float*)d_in[4];
  float* y = (float*)d_out;                  // [T*H] then loss at [T*H]

  char* ws = (char*)d_ws;
  size_t o = 0;
  auto alloc = [&](size_t bytes) { size_t r = o; o = (o + bytes + 255) & ~(size_t)255; return r; };
  size_t o_meta    = alloc(256);              // p_sum[8],lse2,counts[8],cursors[8],n_slots,n_slots2
  size_t o_offsets = alloc(EDIM * 4);
  size_t o_slot_e  = alloc(MAX_SLOTS * 4);
  size_t o_slot_m0 = alloc(MAX_SLOTS * 4);
  size_t o_slot_nr = alloc(MAX_SLOTS * 4);
  size_t o_slot2_e = alloc(MAX_SLOTS2 * 4);
  size_t o_slot2_m0= alloc(MAX_SLOTS2 * 4);
  size_t o_slot2_nr= alloc(MAX_SLOTS2 * 4);
  size_t o_eid     = alloc((size_t)T_TOK * 2 * 4);
  size_t o_tgate   = alloc((size_t)T_TOK * 2 * 4);
  size_t o_tpos    = alloc((size_t)T_TOK * 2 * 4);
  size_t o_btok    = alloc((size_t)TKROW * 4);
  size_t o_bgate   = alloc((size_t)TKROW * 4);
  size_t o_xb      = alloc((size_t)T_TOK * HDIM * 2);
  size_t o_winT    = alloc((size_t)EDIM * N2F * HDIM * 2);  // 64 MiB
  size_t o_woutT   = alloc((size_t)EDIM * HDIM * FDIM * 2); // 32 MiB
  size_t o_glu     = alloc((size_t)TKROW * FDIM * 2);       // 32 MiB
  // orows (32 MiB) ALIASES winT: winT is dead after gemm1, orows is written by
  // gemm2 and read by combine, both strictly later in stream order. Keeps the
  // total workspace footprint at the proven-safe ~136.5 MiB (round-0 size).
  size_t o_orows   = o_winT;
  (void)ws_size;

  float* p_sum   = (float*)(ws + o_meta);
  float* lse2    = (float*)(ws + o_meta + 32);
  int*   counts  = (int*)(ws + o_meta + 64);
  int*   cursors = (int*)(ws + o_meta + 96);
  int*   n_slots = (int*)(ws + o_meta + 128);
  int*   n_slots2= (int*)(ws + o_meta + 132);
  int*   offsets = (int*)(ws + o_offsets);
  int*   slot_e  = (int*)(ws + o_slot_e);
  int*   slot_m0 = (int*)(ws + o_slot_m0);
  int*   slot_nr = (int*)(ws + o_slot_nr);
  int*   slot2_e = (int*)(ws + o_slot2_e);
  int*   slot2_m0= (int*)(ws + o_slot2_m0);
  int*   slot2_nr= (int*)(ws + o_slot2_nr);
  int*   eid     = (int*)(ws + o_eid);
  float* tgate   = (float*)(ws + o_tgate);
  int*   tpos    = (int*)(ws + o_tpos);
  int*   btok    = (int*)(ws + o_btok);
  float* bgate   = (float*)(ws + o_bgate);
  unsigned short* xb    = (unsigned short*)(ws + o_xb);
  unsigned short* winT  = (unsigned short*)(ws + o_winT);
  unsigned short* woutT = (unsigned short*)(ws + o_woutT);
  unsigned short* glu   = (unsigned short*)(ws + o_glu);
  float* orows = (float*)(ws + o_orows);

  hipMemsetAsync(ws, 0, 256, stream);

  // weight conversions
  transpose_conv_kernel<<<dim3(N2F / 64, HDIM / 64, EDIM), dim3(256), 0, stream>>>(
      w_in, winT, HDIM, N2F);
  transpose_conv_kernel<<<dim3(HDIM / 64, FDIM / 64, EDIM), dim3(256), 0, stream>>>(
      w_out, woutT, FDIM, HDIM);

  // routing (also produces xb, the bf16 copy of x)
  router_kernel<<<dim3(256), dim3(256), 0, stream>>>(
      x, w_router, xb, eid, tgate, p_sum, lse2, counts);
  scan_kernel<<<dim3(1), dim3(256), 0, stream>>>(
      counts, offsets, slot_e, slot_m0, slot_nr, n_slots,
      slot2_e, slot2_m0, slot2_nr, n_slots2, cursors);
  scatter_kernel<<<dim3(T_TOK / 256), dim3(256), 0, stream>>>(
      eid, tgate, offsets, cursors, btok, bgate, tpos);

  // expert GEMMs (gemm1 reads winT; gemm2 then overwrites that region as orows)
  gemm1_kernel<<<dim3(MAX_SLOTS, FDIM / 64), dim3(256), 0, stream>>>(
      xb, winT, btok, slot_e, slot_m0, slot_nr, n_slots, glu);
  gemm2_kernel<<<dim3(MAX_SLOTS2, HDIM / 128), dim3(256), 0, stream>>>(
      glu, woutT, bgate, slot2_e, slot2_m0, slot2_nr, n_slots2, orows);

  // combine + loss
  combine_kernel<<<dim3((T_TOK * HDIM) / 1024), dim3(256), 0, stream>>>(
      orows, tpos, bias, y);
  finalize_kernel<<<dim3(1), dim3(1), 0, stream>>>(
      p_sum, lse2, counts, y + (size_t)T_TOK * HDIM);
}